// Round 1
// baseline (1966.429 us; speedup 1.0000x reference)
//
#include <hip/hip_runtime.h>

// StyleConv3D: B=8, Cin=32, Cout=32, D=48, K=3, VALID conv -> Dout=46
// d_in: x(8,32,48,48,48) f32 | s(8,2) | style_weight(32,2) | style_bias(32)
//       | weight(32,32,3,3,3) | bias(32)
// d_out: (8,32,46,46,46) f32
// d_ws: w_n[b][cout][cin][k] = 8*32*32*27 floats = 884,736 bytes

#define B_    8
#define CIN   32
#define COUT  32
#define DI    48
#define DO    46
#define KVOL  27
#define WPB   (CIN * KVOL)   // 864 weights per (b,cout)

// ---------------- Kernel A: modulate + demodulate weights ----------------
__global__ __launch_bounds__(64) void wnorm_kernel(
    const float* __restrict__ s,   // (B,2)
    const float* __restrict__ sw,  // (Cin,2)
    const float* __restrict__ sb,  // (Cin,)
    const float* __restrict__ w,   // (Cout,Cin,27)
    float* __restrict__ wn)        // (B,Cout,Cin,27)
{
    int bc = blockIdx.x;           // b*32 + cout
    int b  = bc >> 5;
    int co = bc & 31;
    int lane = threadIdx.x;

    float s0 = s[b * 2 + 0], s1 = s[b * 2 + 1];

    float sum = 0.f;
    for (int i = lane; i < WPB; i += 64) {
        int cin = i / KVOL;
        float m = fmaf(s0, sw[cin * 2 + 0], fmaf(s1, sw[cin * 2 + 1], sb[cin]));
        float v = w[co * WPB + i] * m;
        sum += v * v;
    }
#pragma unroll
    for (int off = 32; off; off >>= 1) sum += __shfl_xor(sum, off, 64);

    float rn = 1.0f / sqrtf(sum + 1e-8f);

    for (int i = lane; i < WPB; i += 64) {
        int cin = i / KVOL;
        float m = fmaf(s0, sw[cin * 2 + 0], fmaf(s1, sw[cin * 2 + 1], sb[cin]));
        wn[(size_t)bc * WPB + i] = w[co * WPB + i] * m * rn;
    }
}

// ---------------- Kernel B: direct conv, LDS input tile, SGPR weights ----
#define CO_T 8     // couts per thread
#define ZT   4
#define YT   4
#define XT   16
#define CCH  8     // cin chunk
#define SXD  (XT + 2)   // 18
#define SYD  (YT + 2)   // 6
#define SZD  (ZT + 2)   // 6
#define NXT  3     // ceil(46/16)
#define NYT  12    // ceil(46/4)
#define NZT  12

__global__ __launch_bounds__(256) void conv_kernel(
    const float* __restrict__ xin,   // (B,Cin,48,48,48)
    const float* __restrict__ wn,    // (B,Cout,Cin,27)
    const float* __restrict__ bias,  // (Cout,)
    float* __restrict__ out)         // (B,Cout,46,46,46)
{
    __shared__ float sx[CCH][SZD][SYD][SXD];

    int blk = blockIdx.x;
    int xt = blk % NXT; blk /= NXT;
    int yt = blk % NYT; blk /= NYT;
    int zt = blk % NZT; blk /= NZT;
    int cg = blk & 3;   blk >>= 2;
    int b  = blk;                      // 0..7

    int t  = threadIdx.x;
    int tx = t & 15, ty = (t >> 4) & 3, tz = t >> 6;
    int x0 = xt * XT, y0 = yt * YT, z0 = zt * ZT;
    int cob = cg * CO_T;

    float acc[CO_T];
#pragma unroll
    for (int i = 0; i < CO_T; i++) acc[i] = 0.f;

    const float* wb = wn + (size_t)(b * COUT + cob) * WPB;

    for (int cc = 0; cc < CIN; cc += CCH) {
        __syncthreads();   // protect previous chunk's reads
        // ---- stage input tile (8 cin x 6 x 6 x 18) ----
        for (int i = t; i < CCH * SZD * SYD * SXD; i += 256) {
            int xx = i % SXD;  int r = i / SXD;
            int yy = r % SYD;  r /= SYD;
            int zz = r % SZD;  int ci = r / SZD;
            int gx = x0 + xx, gy = y0 + yy, gz = z0 + zz;
            float v = 0.f;
            if (gx < DI && gy < DI && gz < DI)
                v = xin[(((size_t)(b * CIN + cc + ci) * DI + gz) * DI + gy) * DI + gx];
            sx[ci][zz][yy][xx] = v;
        }
        __syncthreads();

        // ---- compute ----
#pragma unroll
        for (int ci = 0; ci < CCH; ci++) {
            float xv[KVOL];
#pragma unroll
            for (int dz = 0; dz < 3; dz++)
#pragma unroll
                for (int dy = 0; dy < 3; dy++)
#pragma unroll
                    for (int dx = 0; dx < 3; dx++)
                        xv[dz * 9 + dy * 3 + dx] = sx[ci][tz + dz][ty + dy][tx + dx];

            const float* wp = wb + (cc + ci) * KVOL;   // uniform address -> s_load
#pragma unroll
            for (int co = 0; co < CO_T; co++) {
#pragma unroll
                for (int k = 0; k < KVOL; k++)
                    acc[co] = fmaf(xv[k], wp[(size_t)co * WPB + k], acc[co]);
            }
        }
    }

    int ox = x0 + tx, oy = y0 + ty, oz = z0 + tz;
    if (ox < DO && oy < DO && oz < DO) {
#pragma unroll
        for (int co = 0; co < CO_T; co++) {
            size_t oidx = ((((size_t)(b * COUT + cob + co)) * DO + oz) * DO + oy) * DO + ox;
            out[oidx] = acc[co] + bias[cob + co];
        }
    }
}

extern "C" void kernel_launch(void* const* d_in, const int* in_sizes, int n_in,
                              void* d_out, int out_size, void* d_ws, size_t ws_size,
                              hipStream_t stream) {
    const float* x    = (const float*)d_in[0];
    const float* s    = (const float*)d_in[1];
    const float* sw   = (const float*)d_in[2];
    const float* sb   = (const float*)d_in[3];
    const float* w    = (const float*)d_in[4];
    const float* bias = (const float*)d_in[5];
    float* out = (float*)d_out;
    float* wnp = (float*)d_ws;   // 884,736 bytes

    hipLaunchKernelGGL(wnorm_kernel, dim3(B_ * COUT), dim3(64), 0, stream,
                       s, sw, sb, w, wnp);
    hipLaunchKernelGGL(conv_kernel, dim3(NXT * NYT * NZT * 4 * B_), dim3(256), 0, stream,
                       x, wnp, bias, out);
}

// Round 2
// 136.189 us; speedup vs baseline: 14.4389x; 14.4389x over previous
//
#include <hip/hip_runtime.h>

// StyleConv3D implicit-GEMM on bf16 MFMA (gfx950).
// B=8, Cin=32, Cout=32, D=48, K=3, VALID -> Dout=46.
// GEMM per batch: Y[cout=32][N=spatial] = W[32 x 864] * X[864 x N]
// K order: chunk(2 x 16ci) -> tap(27, padded to 28) x ci16, i.e.
// k_local = tap*16 + ci16. One mfma_f32_16x16x32_bf16 k-step covers
// kk=0..31 = {tap even/odd} x {ci16 0..15}.
//
// d_ws: wA bf16 [b][chunk2][cout32][tap28][ci16] = 8*2*32*28*16*2B = 458,752 B
//       (tap 27 zeroed -> pads K to 448 per chunk).

typedef unsigned short u16;
typedef __bf16 bf16x8 __attribute__((ext_vector_type(8)));
typedef u16 u16x8 __attribute__((ext_vector_type(8)));
typedef float f32x4 __attribute__((ext_vector_type(4)));

__device__ inline u16 f2bf(float f) {
    union { float f; unsigned u; } v; v.f = f;
    unsigned r = (v.u + 0x7FFFu + ((v.u >> 16) & 1u)) >> 16;
    return (u16)r;
}

// ---------------- Kernel A: modulate + demodulate -> bf16 A-layout --------
__global__ __launch_bounds__(64) void wnorm_kernel(
    const float* __restrict__ s,   // (8,2)
    const float* __restrict__ sw,  // (32,2)
    const float* __restrict__ sb,  // (32,)
    const float* __restrict__ w,   // (32,32,27)
    u16* __restrict__ wA)          // [b][chunk][cout][tap28][ci16]
{
    int bc = blockIdx.x;          // b*32 + cout
    int b = bc >> 5, co = bc & 31;
    int lane = threadIdx.x;

    float s0 = s[2 * b], s1 = s[2 * b + 1];

    float sum = 0.f;
    for (int i = lane; i < 864; i += 64) {
        int ci = i / 27;
        float m = fmaf(s0, sw[2 * ci], fmaf(s1, sw[2 * ci + 1], sb[ci]));
        float v = w[co * 864 + i] * m;
        sum += v * v;
    }
#pragma unroll
    for (int off = 32; off; off >>= 1) sum += __shfl_xor(sum, off, 64);
    float rn = 1.0f / sqrtf(sum + 1e-8f);

    for (int i = lane; i < 864; i += 64) {
        int ci = i / 27, tap = i - ci * 27;
        float m = fmaf(s0, sw[2 * ci], fmaf(s1, sw[2 * ci + 1], sb[ci]));
        float v = w[co * 864 + i] * m * rn;
        int chunk = ci >> 4, ci16 = ci & 15;
        wA[(((b * 2 + chunk) * 32 + co) * 28 + tap) * 16 + ci16] = f2bf(v);
    }
    // zero the pad tap (tap==27) for both chunks
    if (lane < 32) {
        int c = lane >> 4, ci16 = lane & 15;
        wA[(((b * 2 + c) * 32 + co) * 28 + 27) * 16 + ci16] = 0;
    }
}

// ---------------- Kernel B: implicit-GEMM conv ----------------------------
// Block: (b, zt, yt): outputs z0..z0+3, y0..y0+3, x 0..47 (mask x,y,z >= 46).
// LDS x-tile: [z 6][y 6][ch 2][x 50][ci8 8] bf16 = 57,600 B, one 16-ci chunk.
// 8 waves: wave w -> z = w&3, y-pair = w>>2; 2(y) x 3(x16) tiles, 2 cout halves.
__global__ __launch_bounds__(512) void conv_mfma(
    const float* __restrict__ xin,   // (8,32,48,48,48) f32
    const u16* __restrict__ wA,
    const float* __restrict__ bias,  // (32,)
    float* __restrict__ out)         // (8,32,46,46,46) f32
{
    __shared__ u16 sx[28800];

    int blk = blockIdx.x;
    int zt = blk % 12, yt = (blk / 12) % 12, b = blk / 144;
    int z0 = zt * 4, y0 = yt * 4;

    int t = threadIdx.x;
    int l = t & 63, w = t >> 6;
    int ln = l & 15;            // MFMA col (x within 16-tile)
    int ch = (l >> 4) & 1;      // ci half (0..7 / 8..15)
    int tp = l >> 5;            // tap parity
    int rg = l >> 4;            // C-layout row group (0..3)
    int zw = w & 3, yp = w >> 2;

    f32x4 acc[2][3][2];         // [y-row][x-tile][cout-half]
#pragma unroll
    for (int i = 0; i < 2; i++)
#pragma unroll
        for (int j = 0; j < 3; j++)
#pragma unroll
            for (int h = 0; h < 2; h++) acc[i][j][h] = (f32x4)0.f;

    for (int chunk = 0; chunk < 2; ++chunk) {
        __syncthreads();   // protect previous chunk's LDS reads
        // ---- stage: 50x6x6 sites x 16 ci (as 2 groups of 8) ----
        for (int idx = t; idx < 3600; idx += 512) {
            int x = idx % 50;
            int r = idx / 50;
            int cg = r & 1; r >>= 1;
            int y = r % 6, z = r / 6;
            int gz = z0 + z, gy = y0 + y;
            bool inb = (x < 48) && (gy < 48) && (gz < 48);
            const float* xp = xin + (size_t)(b * 32 + chunk * 16 + cg * 8) * 110592
                              + gz * 2304 + gy * 48 + x;
            u16x8 v;
#pragma unroll
            for (int j = 0; j < 8; j++) {
                float f = inb ? xp[(size_t)j * 110592] : 0.f;
                v[j] = f2bf(f);
            }
            *(u16x8*)&sx[idx * 8] = v;   // layout order == idx order
        }
        __syncthreads();

        const u16* wAc = wA + (b * 2 + chunk) * (32 * 28 * 16);
        // lane A offset: (cout*28 + tap)*16 + ch*8, cout = ln + 16h, tap = 2s+tp
        int aoff = (ln * 28 + tp) * 16 + ch * 8;

#pragma unroll
        for (int s = 0; s < 14; ++s) {
            int tapA = 2 * s + tp;                 // may be 27 -> zero pad row
            bf16x8 A0 = __builtin_bit_cast(bf16x8, *(const u16x8*)(wAc + aoff + s * 32));
            bf16x8 A1 = __builtin_bit_cast(bf16x8, *(const u16x8*)(wAc + aoff + 16 * 28 * 16 + s * 32));
            int tapB = tapA > 26 ? 26 : tapA;      // clamp for LDS bounds (A=0 there)
            int dz = tapB / 9;
            int rr = tapB - dz * 9;
            int dy = rr / 3;
            int dx = rr - dy * 3;
            int zr = zw + dz;
#pragma unroll
            for (int yr = 0; yr < 2; ++yr) {
                int yy = 2 * yp + yr + dy;
                int eb = (((zr * 6 + yy) * 2 + ch) * 50 + ln + dx) * 8;
#pragma unroll
                for (int xt = 0; xt < 3; ++xt) {
                    bf16x8 Bf = __builtin_bit_cast(bf16x8, *(const u16x8*)&sx[eb + xt * 128]);
                    acc[yr][xt][0] = __builtin_amdgcn_mfma_f32_16x16x32_bf16(A0, Bf, acc[yr][xt][0], 0, 0, 0);
                    acc[yr][xt][1] = __builtin_amdgcn_mfma_f32_16x16x32_bf16(A1, Bf, acc[yr][xt][1], 0, 0, 0);
                }
            }
        }
    }

    // ---- store: C layout col=lane&15 (x), row=(lane>>4)*4+reg (cout) ----
    int oz = z0 + zw;
    if (oz < 46) {
#pragma unroll
        for (int yr = 0; yr < 2; ++yr) {
            int oy = y0 + 2 * yp + yr;
            if (oy >= 46) continue;
#pragma unroll
            for (int xt = 0; xt < 3; ++xt) {
                int ox = xt * 16 + ln;
                if (ox >= 46) continue;
#pragma unroll
                for (int h = 0; h < 2; ++h) {
                    f32x4 a = acc[yr][xt][h];
#pragma unroll
                    for (int r = 0; r < 4; ++r) {
                        int co = h * 16 + rg * 4 + r;
                        out[(size_t)(b * 32 + co) * 97336 + oz * 2116 + oy * 46 + ox]
                            = a[r] + bias[co];
                    }
                }
            }
        }
    }
}

extern "C" void kernel_launch(void* const* d_in, const int* in_sizes, int n_in,
                              void* d_out, int out_size, void* d_ws, size_t ws_size,
                              hipStream_t stream) {
    const float* x    = (const float*)d_in[0];
    const float* s    = (const float*)d_in[1];
    const float* sw   = (const float*)d_in[2];
    const float* sb   = (const float*)d_in[3];
    const float* wgt  = (const float*)d_in[4];
    const float* bias = (const float*)d_in[5];
    float* out = (float*)d_out;
    u16* wA = (u16*)d_ws;

    hipLaunchKernelGGL(wnorm_kernel, dim3(256), dim3(64), 0, stream,
                       s, sw, sb, wgt, wA);
    hipLaunchKernelGGL(conv_mfma, dim3(12 * 12 * 8), dim3(512), 0, stream,
                       x, wA, bias, out);
}